// Round 1
// baseline (235.137 us; speedup 1.0000x reference)
//
#include <hip/hip_runtime.h>

// CtaPostAttnMixer: y = (I + 0.1*Lap)^4 x along l, boundaries l=0, L-1 fixed.
// Composed into one 9-tap convolution (interior) + analytic boundary rows.
// x: (B=4, L=8192, D=1024) f32, D contiguous. One thread = one float4 d-quad,
// streaming a SEG=64 l-range as 4 chunks of 16 with a rolling 24-reg window.

namespace {

constexpr int Lr   = 8192;          // sequence length
constexpr int Dq   = 1024 / 4;      // float4 columns = 256
constexpr int Bn   = 4;             // batch
constexpr int C    = 16;            // chunk length along l
constexpr int H    = 8;             // total halo (4 each side)
constexpr int SEG  = 64;            // l-span per thread
constexpr int SEGS = Lr / SEG;      // 128

// standard 9-tap weights of (I + a*Lap)^4, a = 0.1  (symmetric)
constexpr float WK0 = 0.4870f;  // |k| = 0
constexpr float WK1 = 0.2144f;  // |k| = 1
constexpr float WK2 = 0.0388f;  // |k| = 2
constexpr float WK3 = 0.0032f;  // |k| = 3
constexpr float WK4 = 0.0001f;  // |k| = 4

__device__ __forceinline__ float4 f4_add(float4 a, float4 b) {
    return make_float4(a.x + b.x, a.y + b.y, a.z + b.z, a.w + b.w);
}
__device__ __forceinline__ float4 f4_mul(float s, float4 a) {
    return make_float4(s * a.x, s * a.y, s * a.z, s * a.w);
}
__device__ __forceinline__ float4 f4_fma(float s, float4 a, float4 c) {
    return make_float4(fmaf(s, a.x, c.x), fmaf(s, a.y, c.y),
                       fmaf(s, a.z, c.z), fmaf(s, a.w, c.w));
}

__global__ __launch_bounds__(256)
void mixer4_kernel(const float4* __restrict__ x, float4* __restrict__ y) {
    const int d4  = threadIdx.x;        // 0..255  (float4 column)
    const int seg = blockIdx.x;         // 0..SEGS-1
    const int b   = blockIdx.y;         // 0..3
    const int c_base = seg * SEG;

    const float4* __restrict__ xb = x + (size_t)b * Lr * Dq + d4;
    float4* __restrict__       yb = y + (size_t)b * Lr * Dq + d4;

    float4 w[C + H];  // raw input window: w[i] = x[c0 - 4 + i]

    // initial window for chunk 0: gl = c_base-4 .. c_base+19 (clamped)
#pragma unroll
    for (int i = 0; i < C + H; ++i) {
        int gl = c_base - 4 + i;
        gl = gl < 0 ? 0 : gl;
        gl = gl > Lr - 1 ? Lr - 1 : gl;
        w[i] = xb[(size_t)gl * Dq];
    }

#pragma unroll
    for (int chunk = 0; chunk < SEG / C; ++chunk) {
        const int c0 = c_base + chunk * C;

        if (chunk > 0) {
            // shift carried halo, load C new rows: gl = c0+4 .. c0+19
#pragma unroll
            for (int i = 0; i < H; ++i) w[i] = w[C + i];
#pragma unroll
            for (int i = H; i < C + H; ++i) {
                int gl = c0 - 4 + i;
                gl = gl > Lr - 1 ? Lr - 1 : gl;
                w[i] = xb[(size_t)gl * Dq];
            }
        }

        // standard 9-tap conv for all 16 outputs, store immediately
#pragma unroll
        for (int j = 0; j < C; ++j) {
            float4 acc = f4_mul(WK0, w[j + 4]);
            acc = f4_fma(WK1, f4_add(w[j + 3], w[j + 5]), acc);
            acc = f4_fma(WK2, f4_add(w[j + 2], w[j + 6]), acc);
            acc = f4_fma(WK3, f4_add(w[j + 1], w[j + 7]), acc);
            acc = f4_fma(WK4, f4_add(w[j + 0], w[j + 8]), acc);
            yb[(size_t)(c0 + j) * Dq] = acc;
        }

        // ---- boundary overrides (uniform branches, 2 chunks of 2048) ----
        if (c0 == 0) {
            // l=0: copy
            yb[0] = w[4];
            // l=1: row1 over x[0..5] = w[4..9]
            {
                float4 o = f4_mul(0.2986f, w[4]);
                o = f4_fma(0.4482f, w[5], o);
                o = f4_fma(0.2112f, w[6], o);
                o = f4_fma(0.0387f, w[7], o);
                o = f4_fma(0.0032f, w[8], o);
                o = f4_fma(0.0001f, w[9], o);
                yb[(size_t)1 * Dq] = o;
            }
            // l=2: row2 over x[0..6] = w[4..10]
            {
                float4 o = f4_mul(0.0454f, w[4]);
                o = f4_fma(0.2112f, w[5], o);
                o = f4_fma(0.4869f, w[6], o);
                o = f4_fma(0.2144f, w[7], o);
                o = f4_fma(0.0388f, w[8], o);
                o = f4_fma(0.0032f, w[9], o);
                o = f4_fma(0.0001f, w[10], o);
                yb[(size_t)2 * Dq] = o;
            }
            // l=3: row3 over x[0..7] = w[4..11]
            {
                float4 o = f4_mul(0.0034f, w[4]);
                o = f4_fma(0.0387f, w[5], o);
                o = f4_fma(0.2144f, w[6], o);
                o = f4_fma(0.4870f, w[7], o);
                o = f4_fma(0.2144f, w[8], o);
                o = f4_fma(0.0388f, w[9], o);
                o = f4_fma(0.0032f, w[10], o);
                o = f4_fma(0.0001f, w[11], o);
                yb[(size_t)3 * Dq] = o;
            }
        }
        if (c0 == Lr - C) {
            // w[19] = x[L-1], w[19-p] = x[L-1-p]
            // l = L-1: copy
            yb[(size_t)(Lr - 1) * Dq] = w[19];
            // l = L-2: mirrored row1
            {
                float4 o = f4_mul(0.2986f, w[19]);
                o = f4_fma(0.4482f, w[18], o);
                o = f4_fma(0.2112f, w[17], o);
                o = f4_fma(0.0387f, w[16], o);
                o = f4_fma(0.0032f, w[15], o);
                o = f4_fma(0.0001f, w[14], o);
                yb[(size_t)(Lr - 2) * Dq] = o;
            }
            // l = L-3: mirrored row2
            {
                float4 o = f4_mul(0.0454f, w[19]);
                o = f4_fma(0.2112f, w[18], o);
                o = f4_fma(0.4869f, w[17], o);
                o = f4_fma(0.2144f, w[16], o);
                o = f4_fma(0.0388f, w[15], o);
                o = f4_fma(0.0032f, w[14], o);
                o = f4_fma(0.0001f, w[13], o);
                yb[(size_t)(Lr - 3) * Dq] = o;
            }
            // l = L-4: mirrored row3
            {
                float4 o = f4_mul(0.0034f, w[19]);
                o = f4_fma(0.0387f, w[18], o);
                o = f4_fma(0.2144f, w[17], o);
                o = f4_fma(0.4870f, w[16], o);
                o = f4_fma(0.2144f, w[15], o);
                o = f4_fma(0.0388f, w[14], o);
                o = f4_fma(0.0032f, w[13], o);
                o = f4_fma(0.0001f, w[12], o);
                yb[(size_t)(Lr - 4) * Dq] = o;
            }
        }
    }
}

}  // namespace

extern "C" void kernel_launch(void* const* d_in, const int* in_sizes, int n_in,
                              void* d_out, int out_size, void* d_ws, size_t ws_size,
                              hipStream_t stream) {
    const float4* x = (const float4*)d_in[0];
    float4*       y = (float4*)d_out;

    dim3 grid(SEGS, Bn);   // 128 x 4 = 512 blocks
    dim3 block(256);       // 256 threads = full D (256 float4 columns)
    hipLaunchKernelGGL(mixer4_kernel, grid, block, 0, stream, x, y);
}

// Round 3
// 234.909 us; speedup vs baseline: 1.0010x; 1.0010x over previous
//
#include <hip/hip_runtime.h>

// CtaPostAttnMixer: y = (I + 0.1*Lap)^4 x along l, boundaries l=0, L-1 fixed.
// Composed into one 9-tap convolution (interior) + analytic boundary rows.
// x: (B=4, L=8192, D=1024) f32, D contiguous. One thread = one float4 d-quad
// over a 16-row l-chunk (24-row raw window incl. 4-row halo each side).
//
// R1 lesson: SEG=64 gave only 2 waves/SIMD -> latency-bound at 2.5 TB/s
// (Occupancy 17.5%, VALUBusy 5%). SEG=16 -> 2048 blocks = 32 waves/CU (max).
// R2 lesson: __builtin_nontemporal_store needs a NATIVE clang vector type,
// not HIP_vector_type<float,4> -- reinterpret through ext_vector_type(4).

namespace {

constexpr int Lr   = 8192;          // sequence length
constexpr int Dq   = 1024 / 4;      // float4 columns = 256
constexpr int Bn   = 4;             // batch
constexpr int C    = 16;            // chunk length along l (= per-thread span)
constexpr int H    = 8;             // total halo (4 each side)
constexpr int SEGS = Lr / C;        // 512

// standard 9-tap weights of (I + a*Lap)^4, a = 0.1  (symmetric)
constexpr float WK0 = 0.4870f;  // |k| = 0
constexpr float WK1 = 0.2144f;  // |k| = 1
constexpr float WK2 = 0.0388f;  // |k| = 2
constexpr float WK3 = 0.0032f;  // |k| = 3
constexpr float WK4 = 0.0001f;  // |k| = 4

typedef float nfloat4 __attribute__((ext_vector_type(4)));  // native vec4

__device__ __forceinline__ float4 f4_add(float4 a, float4 b) {
    return make_float4(a.x + b.x, a.y + b.y, a.z + b.z, a.w + b.w);
}
__device__ __forceinline__ float4 f4_mul(float s, float4 a) {
    return make_float4(s * a.x, s * a.y, s * a.z, s * a.w);
}
__device__ __forceinline__ float4 f4_fma(float s, float4 a, float4 c) {
    return make_float4(fmaf(s, a.x, c.x), fmaf(s, a.y, c.y),
                       fmaf(s, a.z, c.z), fmaf(s, a.w, c.w));
}
__device__ __forceinline__ void f4_store_nt(float4* p, float4 v) {
    nfloat4 nv;
    nv.x = v.x; nv.y = v.y; nv.z = v.z; nv.w = v.w;
    __builtin_nontemporal_store(nv, (nfloat4*)p);
}

__global__ __launch_bounds__(256)
void mixer4_kernel(const float4* __restrict__ x, float4* __restrict__ y) {
    const int d4  = threadIdx.x;        // 0..255  (float4 column)
    const int seg = blockIdx.x;         // 0..SEGS-1
    const int b   = blockIdx.y;         // 0..3
    const int c0  = seg * C;

    const float4* __restrict__ xb = x + (size_t)b * Lr * Dq + d4;
    float4* __restrict__       yb = y + (size_t)b * Lr * Dq + d4;

    float4 w[C + H];  // raw input window: w[i] = x[c0 - 4 + i]

#pragma unroll
    for (int i = 0; i < C + H; ++i) {
        int gl = c0 - 4 + i;
        gl = gl < 0 ? 0 : gl;
        gl = gl > Lr - 1 ? Lr - 1 : gl;
        w[i] = xb[(size_t)gl * Dq];
    }

    // standard 9-tap conv for all 16 outputs, store immediately (streaming)
#pragma unroll
    for (int j = 0; j < C; ++j) {
        float4 acc = f4_mul(WK0, w[j + 4]);
        acc = f4_fma(WK1, f4_add(w[j + 3], w[j + 5]), acc);
        acc = f4_fma(WK2, f4_add(w[j + 2], w[j + 6]), acc);
        acc = f4_fma(WK3, f4_add(w[j + 1], w[j + 7]), acc);
        acc = f4_fma(WK4, f4_add(w[j + 0], w[j + 8]), acc);
        f4_store_nt(&yb[(size_t)(c0 + j) * Dq], acc);
    }

    // ---- boundary overrides (uniform branches, 2 blocks of 2048) ----
    if (c0 == 0) {
        // l=0: copy
        f4_store_nt(&yb[0], w[4]);
        // l=1: row1 over x[0..5] = w[4..9]
        {
            float4 o = f4_mul(0.2986f, w[4]);
            o = f4_fma(0.4482f, w[5], o);
            o = f4_fma(0.2112f, w[6], o);
            o = f4_fma(0.0387f, w[7], o);
            o = f4_fma(0.0032f, w[8], o);
            o = f4_fma(0.0001f, w[9], o);
            f4_store_nt(&yb[(size_t)1 * Dq], o);
        }
        // l=2: row2 over x[0..6] = w[4..10]
        {
            float4 o = f4_mul(0.0454f, w[4]);
            o = f4_fma(0.2112f, w[5], o);
            o = f4_fma(0.4869f, w[6], o);
            o = f4_fma(0.2144f, w[7], o);
            o = f4_fma(0.0388f, w[8], o);
            o = f4_fma(0.0032f, w[9], o);
            o = f4_fma(0.0001f, w[10], o);
            f4_store_nt(&yb[(size_t)2 * Dq], o);
        }
        // l=3: row3 over x[0..7] = w[4..11]
        {
            float4 o = f4_mul(0.0034f, w[4]);
            o = f4_fma(0.0387f, w[5], o);
            o = f4_fma(0.2144f, w[6], o);
            o = f4_fma(0.4870f, w[7], o);
            o = f4_fma(0.2144f, w[8], o);
            o = f4_fma(0.0388f, w[9], o);
            o = f4_fma(0.0032f, w[10], o);
            o = f4_fma(0.0001f, w[11], o);
            f4_store_nt(&yb[(size_t)3 * Dq], o);
        }
    }
    if (c0 == Lr - C) {
        // w[19] = x[L-1], w[19-p] = x[L-1-p]
        // l = L-1: copy
        f4_store_nt(&yb[(size_t)(Lr - 1) * Dq], w[19]);
        // l = L-2: mirrored row1
        {
            float4 o = f4_mul(0.2986f, w[19]);
            o = f4_fma(0.4482f, w[18], o);
            o = f4_fma(0.2112f, w[17], o);
            o = f4_fma(0.0387f, w[16], o);
            o = f4_fma(0.0032f, w[15], o);
            o = f4_fma(0.0001f, w[14], o);
            f4_store_nt(&yb[(size_t)(Lr - 2) * Dq], o);
        }
        // l = L-3: mirrored row2
        {
            float4 o = f4_mul(0.0454f, w[19]);
            o = f4_fma(0.2112f, w[18], o);
            o = f4_fma(0.4869f, w[17], o);
            o = f4_fma(0.2144f, w[16], o);
            o = f4_fma(0.0388f, w[15], o);
            o = f4_fma(0.0032f, w[14], o);
            o = f4_fma(0.0001f, w[13], o);
            f4_store_nt(&yb[(size_t)(Lr - 3) * Dq], o);
        }
        // l = L-4: mirrored row3
        {
            float4 o = f4_mul(0.0034f, w[19]);
            o = f4_fma(0.0387f, w[18], o);
            o = f4_fma(0.2144f, w[17], o);
            o = f4_fma(0.4870f, w[16], o);
            o = f4_fma(0.2144f, w[15], o);
            o = f4_fma(0.0388f, w[14], o);
            o = f4_fma(0.0032f, w[13], o);
            o = f4_fma(0.0001f, w[12], o);
            f4_store_nt(&yb[(size_t)(Lr - 4) * Dq], o);
        }
    }
}

}  // namespace

extern "C" void kernel_launch(void* const* d_in, const int* in_sizes, int n_in,
                              void* d_out, int out_size, void* d_ws, size_t ws_size,
                              hipStream_t stream) {
    const float4* x = (const float4*)d_in[0];
    float4*       y = (float4*)d_out;

    dim3 grid(SEGS, Bn);   // 512 x 4 = 2048 blocks -> 8192 waves = 32/CU
    dim3 block(256);       // 256 threads = full D (256 float4 columns)
    hipLaunchKernelGGL(mixer4_kernel, grid, block, 0, stream, x, y);
}

// Round 4
// 230.510 us; speedup vs baseline: 1.0201x; 1.0191x over previous
//
#include <hip/hip_runtime.h>

// CtaPostAttnMixer: y = (I + 0.1*Lap)^4 x along l, boundaries l=0, L-1 fixed.
// Composed into one 9-tap convolution (interior) + analytic boundary rows.
// x: (B=4, L=8192, D=1024) f32, D contiguous. One thread = one float4 d-quad
// over a 4-row l-chunk (12-row raw window incl. 4-row halo each side).
//
// R1 lesson: SEG=64 -> 2 waves/SIMD, latency-bound 2.5 TB/s.
// R3 lesson: C=16 window (96 VGPR) vs VGPR_Count=48 -> compiler serialized
//   loads into dependent batches; occupancy rose to 41% but BW stuck at
//   2.7 TB/s. Fix: C=4 so the 12-float4 window FITS in registers; all 12
//   loads issue independently (12 KB/wave in flight). launch_bounds(256,8)
//   pins VGPR<=64 -> 32 waves/CU.

namespace {

constexpr int Lr   = 8192;          // sequence length
constexpr int Dq   = 1024 / 4;      // float4 columns = 256
constexpr int Bn   = 4;             // batch
constexpr int C    = 4;             // chunk length along l (= per-thread span)
constexpr int W    = C + 8;         // raw window rows = 12
constexpr int SEGS = Lr / C;        // 2048

// standard 9-tap weights of (I + a*Lap)^4, a = 0.1 (exact: p=[.1,.8,.1]^*4)
constexpr float WK0 = 0.4870f;
constexpr float WK1 = 0.2144f;
constexpr float WK2 = 0.0388f;
constexpr float WK3 = 0.0032f;
constexpr float WK4 = 0.0001f;

typedef float nfloat4 __attribute__((ext_vector_type(4)));  // native vec4

__device__ __forceinline__ float4 f4_add(float4 a, float4 b) {
    return make_float4(a.x + b.x, a.y + b.y, a.z + b.z, a.w + b.w);
}
__device__ __forceinline__ float4 f4_mul(float s, float4 a) {
    return make_float4(s * a.x, s * a.y, s * a.z, s * a.w);
}
__device__ __forceinline__ float4 f4_fma(float s, float4 a, float4 c) {
    return make_float4(fmaf(s, a.x, c.x), fmaf(s, a.y, c.y),
                       fmaf(s, a.z, c.z), fmaf(s, a.w, c.w));
}
__device__ __forceinline__ void f4_store_nt(float4* p, float4 v) {
    nfloat4 nv;
    nv.x = v.x; nv.y = v.y; nv.z = v.z; nv.w = v.w;
    __builtin_nontemporal_store(nv, (nfloat4*)p);
}

__global__ __launch_bounds__(256, 8)   // pin VGPR<=64 -> 32 waves/CU
void mixer4_kernel(const float4* __restrict__ x, float4* __restrict__ y) {
    const int d4  = threadIdx.x;        // 0..255  (float4 column)
    const int seg = blockIdx.x;         // 0..SEGS-1
    const int b   = blockIdx.y;         // 0..3
    const int c0  = seg * C;

    const float4* __restrict__ xb = x + (size_t)b * Lr * Dq + d4;
    float4* __restrict__       yb = y + (size_t)b * Lr * Dq + d4;

    // raw input window: w[i] = x[clamp(c0 - 4 + i)], 12 independent loads
    float4 w[W];
#pragma unroll
    for (int i = 0; i < W; ++i) {
        int gl = c0 - 4 + i;
        gl = gl < 0 ? 0 : gl;
        gl = gl > Lr - 1 ? Lr - 1 : gl;
        w[i] = xb[(size_t)gl * Dq];
    }

    if (c0 != 0 && c0 != Lr - C) {
        // interior: standard 9-tap conv for the 4 outputs
#pragma unroll
        for (int j = 0; j < C; ++j) {
            float4 acc = f4_mul(WK0, w[j + 4]);
            acc = f4_fma(WK1, f4_add(w[j + 3], w[j + 5]), acc);
            acc = f4_fma(WK2, f4_add(w[j + 2], w[j + 6]), acc);
            acc = f4_fma(WK3, f4_add(w[j + 1], w[j + 7]), acc);
            acc = f4_fma(WK4, f4_add(w[j + 0], w[j + 8]), acc);
            f4_store_nt(&yb[(size_t)(c0 + j) * Dq], acc);
        }
    } else if (c0 == 0) {
        // chunk 0: rows l=0..3 are ALL boundary-special. w[4+i] = x[i].
        // l=0: copy
        f4_store_nt(&yb[0], w[4]);
        // l=1
        {
            float4 o = f4_mul(0.2986f, w[4]);
            o = f4_fma(0.4482f, w[5], o);
            o = f4_fma(0.2112f, w[6], o);
            o = f4_fma(0.0387f, w[7], o);
            o = f4_fma(0.0032f, w[8], o);
            o = f4_fma(0.0001f, w[9], o);
            f4_store_nt(&yb[(size_t)1 * Dq], o);
        }
        // l=2
        {
            float4 o = f4_mul(0.0454f, w[4]);
            o = f4_fma(0.2112f, w[5], o);
            o = f4_fma(0.4869f, w[6], o);
            o = f4_fma(0.2144f, w[7], o);
            o = f4_fma(0.0388f, w[8], o);
            o = f4_fma(0.0032f, w[9], o);
            o = f4_fma(0.0001f, w[10], o);
            f4_store_nt(&yb[(size_t)2 * Dq], o);
        }
        // l=3
        {
            float4 o = f4_mul(0.0034f, w[4]);
            o = f4_fma(0.0387f, w[5], o);
            o = f4_fma(0.2144f, w[6], o);
            o = f4_fma(0.4870f, w[7], o);
            o = f4_fma(0.2144f, w[8], o);
            o = f4_fma(0.0388f, w[9], o);
            o = f4_fma(0.0032f, w[10], o);
            o = f4_fma(0.0001f, w[11], o);
            f4_store_nt(&yb[(size_t)3 * Dq], o);
        }
    } else {
        // last chunk: rows l=L-4..L-1 all special (mirrored).
        // w[i] = x[Lr-8+i] for i=0..7 (i>=8 clamped dups). x[Lr-1-p] = w[7-p].
        // l = L-1: copy
        f4_store_nt(&yb[(size_t)(Lr - 1) * Dq], w[7]);
        // l = L-2: mirrored row1
        {
            float4 o = f4_mul(0.2986f, w[7]);
            o = f4_fma(0.4482f, w[6], o);
            o = f4_fma(0.2112f, w[5], o);
            o = f4_fma(0.0387f, w[4], o);
            o = f4_fma(0.0032f, w[3], o);
            o = f4_fma(0.0001f, w[2], o);
            f4_store_nt(&yb[(size_t)(Lr - 2) * Dq], o);
        }
        // l = L-3: mirrored row2
        {
            float4 o = f4_mul(0.0454f, w[7]);
            o = f4_fma(0.2112f, w[6], o);
            o = f4_fma(0.4869f, w[5], o);
            o = f4_fma(0.2144f, w[4], o);
            o = f4_fma(0.0388f, w[3], o);
            o = f4_fma(0.0032f, w[2], o);
            o = f4_fma(0.0001f, w[1], o);
            f4_store_nt(&yb[(size_t)(Lr - 3) * Dq], o);
        }
        // l = L-4: mirrored row3
        {
            float4 o = f4_mul(0.0034f, w[7]);
            o = f4_fma(0.0387f, w[6], o);
            o = f4_fma(0.2144f, w[5], o);
            o = f4_fma(0.4870f, w[4], o);
            o = f4_fma(0.2144f, w[3], o);
            o = f4_fma(0.0388f, w[2], o);
            o = f4_fma(0.0032f, w[1], o);
            o = f4_fma(0.0001f, w[0], o);
            f4_store_nt(&yb[(size_t)(Lr - 4) * Dq], o);
        }
    }
}

}  // namespace

extern "C" void kernel_launch(void* const* d_in, const int* in_sizes, int n_in,
                              void* d_out, int out_size, void* d_ws, size_t ws_size,
                              hipStream_t stream) {
    const float4* x = (const float4*)d_in[0];
    float4*       y = (float4*)d_out;

    dim3 grid(SEGS, Bn);   // 2048 x 4 = 8192 blocks -> 2x oversubscribed
    dim3 block(256);       // 256 threads = full D (256 float4 columns)
    hipLaunchKernelGGL(mixer4_kernel, grid, block, 0, stream, x, y);
}